// Round 9
// baseline (565.898 us; speedup 1.0000x reference)
//
#include <hip/hip_runtime.h>
#include <math.h>

#define D_MODEL 1024
#define N_HEADS 16
#define D_K     64
#define SEQ     2048
#define BATCH   4
#define EPS     1e-5f
#define NT      (SEQ / 64)   // 32 key-tiles

typedef __attribute__((ext_vector_type(8))) short bf16x8;
typedef __attribute__((ext_vector_type(4))) float f32x4;

__device__ __forceinline__ unsigned short f2bf(float f) {
    unsigned u = __float_as_uint(f);
    u += 0x7fff + ((u >> 16) & 1);   // RNE
    return (unsigned short)(u >> 16);
}

#define GLDS16(g, l) __builtin_amdgcn_global_load_lds( \
    (const __attribute__((address_space(1))) void*)(g), \
    (__attribute__((address_space(3))) void*)(l), 16, 0, 0)

// ---------------------------------------------------------------------------
// One-shot f32 -> bf16 convert of x + 4 weight matrices (region table).
// ---------------------------------------------------------------------------
__global__ __launch_bounds__(256) void cvt_all(
    const float* __restrict__ x,
    const float* __restrict__ Wq, const float* __restrict__ Wk,
    const float* __restrict__ Wv, const float* __restrict__ Wo,
    unsigned short* __restrict__ xb,
    unsigned short* __restrict__ wqb, unsigned short* __restrict__ wkb,
    unsigned short* __restrict__ wvb, unsigned short* __restrict__ wob)
{
    size_t i4 = (size_t)blockIdx.x * 256 + threadIdx.x;
    const float* src; unsigned short* dst; size_t off;
    if (i4 < 2097152) { src = x; dst = xb; off = i4; }
    else {
        size_t j = i4 - 2097152;
        int wsel = (int)(j >> 18);          // 0..3
        off = j & 262143;
        switch (wsel) {
            case 0:  src = Wq; dst = wqb; break;
            case 1:  src = Wk; dst = wkb; break;
            case 2:  src = Wv; dst = wvb; break;
            default: src = Wo; dst = wob; break;
        }
    }
    float4 f = ((const float4*)src)[off];
    union { ushort4 u; uint2 v; } o;
    o.u.x = f2bf(f.x); o.u.y = f2bf(f.y); o.u.z = f2bf(f.z); o.u.w = f2bf(f.w);
    ((uint2*)dst)[off] = o.v;
}

// ---------------------------------------------------------------------------
// Fused QKV projection: Ot = x @ Wt^T + bt (bf16 out); Q scaled by 0.125.
// which==2 (V) writes DIRECTLY TRANSPOSED: vt[bh][d][s] (s-contig 4/lane).
// Double-buffered LDS, stage-ahead, ONE barrier per K-step (T3 min recipe).
// grid.x = 24 : [which 0..2][bn 0..7] ; grid.y = 64. 128x128 tile, BK=32.
// ---------------------------------------------------------------------------
__global__ __launch_bounds__(256) void gemm_qkv(
    const unsigned short* __restrict__ A,
    const unsigned short* __restrict__ Bq, const unsigned short* __restrict__ Bk,
    const unsigned short* __restrict__ Bv,
    const float* __restrict__ biq, const float* __restrict__ bik,
    const float* __restrict__ biv,
    unsigned short* __restrict__ Oq, unsigned short* __restrict__ Ok,
    unsigned short* __restrict__ Vt)
{
    const int which = blockIdx.x >> 3;
    const unsigned short* B = which == 0 ? Bq : (which == 1 ? Bk : Bv);
    const float* bias        = which == 0 ? biq : (which == 1 ? bik : biv);
    const float scale        = which == 0 ? 0.125f : 1.0f;

    __shared__ unsigned short As[2][128 * 32];
    __shared__ unsigned short Bs[2][128 * 32];
    const int tid = threadIdx.x;
    const int w = tid >> 6, lane = tid & 63;
    const int l15 = lane & 15, lh = lane >> 4;
    const int wm = w >> 1, wn = w & 1;
    const int bm = blockIdx.y * 128, bn = (blockIdx.x & 7) * 128;
    const int K = D_MODEL, N = D_MODEL;

    const int srow = lane >> 2;
    const int skk  = (lane & 3) * 8;

    f32x4 acc[4][4] = {};

    // prologue: stage tile 0
#pragma unroll
    for (int cc = 0; cc < 2; ++cc) {
        int chunk = w * 2 + cc;
        int row = chunk * 16 + srow;
        GLDS16(A + (size_t)(bm + row) * K + skk, As[0] + chunk * 512);
        GLDS16(B + (size_t)(bn + row) * K + skk, Bs[0] + chunk * 512);
    }
    __syncthreads();

    for (int k0 = 0; k0 < K; k0 += 32) {
        const int cur = (k0 >> 5) & 1;
        if (k0 + 32 < K) {
#pragma unroll
            for (int cc = 0; cc < 2; ++cc) {
                int chunk = w * 2 + cc;
                int row = chunk * 16 + srow;
                GLDS16(A + (size_t)(bm + row) * K + k0 + 32 + skk, As[cur ^ 1] + chunk * 512);
                GLDS16(B + (size_t)(bn + row) * K + k0 + 32 + skk, Bs[cur ^ 1] + chunk * 512);
            }
        }
        bf16x8 af[4], bfr[4];
#pragma unroll
        for (int mi = 0; mi < 4; ++mi)
            af[mi] = *(const bf16x8*)&As[cur][(wm * 64 + mi * 16 + l15) * 32 + lh * 8];
#pragma unroll
        for (int nj = 0; nj < 4; ++nj)
            bfr[nj] = *(const bf16x8*)&Bs[cur][(wn * 64 + nj * 16 + l15) * 32 + lh * 8];
#pragma unroll
        for (int mi = 0; mi < 4; ++mi)
#pragma unroll
            for (int nj = 0; nj < 4; ++nj)
                acc[mi][nj] = __builtin_amdgcn_mfma_f32_16x16x32_bf16(
                    af[mi], bfr[nj], acc[mi][nj], 0, 0, 0);
        if (k0 + 32 < K) __syncthreads();
    }

    if (which == 2) {
        // transposed V write: vt[((b*16+head)*64 + d)*SEQ + s], 4 bf16 along s
#pragma unroll
        for (int mi = 0; mi < 4; ++mi) {
#pragma unroll
            for (int nj = 0; nj < 4; ++nj) {
                int col = bn + wn * 64 + nj * 16 + l15;
                int head = col >> 6, d = col & 63;
                float bv = bias[col];
                int row = bm + wm * 64 + mi * 16 + lh * 4;
                int b = row >> 11, s = row & 2047;
                union { ushort4 u; uint2 v; } o;
                o.u.x = f2bf(acc[mi][nj][0] + bv);
                o.u.y = f2bf(acc[mi][nj][1] + bv);
                o.u.z = f2bf(acc[mi][nj][2] + bv);
                o.u.w = f2bf(acc[mi][nj][3] + bv);
                *(uint2*)&Vt[(((size_t)b * 16 + head) * 64 + d) * SEQ + s] = o.v;
            }
        }
    } else {
        unsigned short* O = which == 0 ? Oq : Ok;
#pragma unroll
        for (int mi = 0; mi < 4; ++mi) {
#pragma unroll
            for (int nj = 0; nj < 4; ++nj) {
                int col = bn + wn * 64 + nj * 16 + l15;
                float bv = bias[col];
#pragma unroll
                for (int r = 0; r < 4; ++r) {
                    int row = bm + wm * 64 + mi * 16 + lh * 4 + r;
                    O[(size_t)row * N + col] = f2bf((acc[mi][nj][r] + bv) * scale);
                }
            }
        }
    }
}

// ---------------------------------------------------------------------------
// Output projection: C = ctx @ Wo^T + bo + residual (fp32 out).
// Double-buffered LDS, stage-ahead, ONE barrier per K-step. 128x128, BK=32.
// ---------------------------------------------------------------------------
__global__ __launch_bounds__(256) void gemm_out(
    const unsigned short* __restrict__ A, const unsigned short* __restrict__ B,
    const float* __restrict__ bias, const float* __restrict__ res,
    float* __restrict__ C)
{
    __shared__ unsigned short As[2][128 * 32];
    __shared__ unsigned short Bs[2][128 * 32];
    const int tid = threadIdx.x;
    const int w = tid >> 6, lane = tid & 63;
    const int l15 = lane & 15, lh = lane >> 4;
    const int wm = w >> 1, wn = w & 1;
    const int bm = blockIdx.y * 128, bn = blockIdx.x * 128;
    const int K = D_MODEL, N = D_MODEL;

    const int srow = lane >> 2;
    const int skk  = (lane & 3) * 8;

    f32x4 acc[4][4] = {};

#pragma unroll
    for (int cc = 0; cc < 2; ++cc) {
        int chunk = w * 2 + cc;
        int row = chunk * 16 + srow;
        GLDS16(A + (size_t)(bm + row) * K + skk, As[0] + chunk * 512);
        GLDS16(B + (size_t)(bn + row) * K + skk, Bs[0] + chunk * 512);
    }
    __syncthreads();

    for (int k0 = 0; k0 < K; k0 += 32) {
        const int cur = (k0 >> 5) & 1;
        if (k0 + 32 < K) {
#pragma unroll
            for (int cc = 0; cc < 2; ++cc) {
                int chunk = w * 2 + cc;
                int row = chunk * 16 + srow;
                GLDS16(A + (size_t)(bm + row) * K + k0 + 32 + skk, As[cur ^ 1] + chunk * 512);
                GLDS16(B + (size_t)(bn + row) * K + k0 + 32 + skk, Bs[cur ^ 1] + chunk * 512);
            }
        }
        bf16x8 af[4], bfr[4];
#pragma unroll
        for (int mi = 0; mi < 4; ++mi)
            af[mi] = *(const bf16x8*)&As[cur][(wm * 64 + mi * 16 + l15) * 32 + lh * 8];
#pragma unroll
        for (int nj = 0; nj < 4; ++nj)
            bfr[nj] = *(const bf16x8*)&Bs[cur][(wn * 64 + nj * 16 + l15) * 32 + lh * 8];
#pragma unroll
        for (int mi = 0; mi < 4; ++mi)
#pragma unroll
            for (int nj = 0; nj < 4; ++nj)
                acc[mi][nj] = __builtin_amdgcn_mfma_f32_16x16x32_bf16(
                    af[mi], bfr[nj], acc[mi][nj], 0, 0, 0);
        if (k0 + 32 < K) __syncthreads();
    }

#pragma unroll
    for (int mi = 0; mi < 4; ++mi) {
#pragma unroll
        for (int nj = 0; nj < 4; ++nj) {
            int col = bn + wn * 64 + nj * 16 + l15;
            float bv = bias[col];
#pragma unroll
            for (int r = 0; r < 4; ++r) {
                int row = bm + wm * 64 + mi * 16 + lh * 4 + r;
                C[(size_t)row * N + col] = acc[mi][nj][r] + bv + res[(size_t)row * N + col];
            }
        }
    }
}

// ---------------------------------------------------------------------------
// Staging helper: stage a 64-row x 128B tile into LDS (linear dest,
// chunk-swizzled global source: lds chunk cs <- global chunk cs ^ (row&7)).
// Read side XORs the same involution -> conflict-free ds_read_b128.
// ---------------------------------------------------------------------------
__device__ __forceinline__ void stage_tile64(
    const unsigned short* __restrict__ gbase, size_t grow_stride,
    unsigned short* lds, int w, int lane)
{
#pragma unroll
    for (int i = 0; i < 2; ++i) {
        int row = i * 32 + w * 8 + (lane >> 3);
        int c   = (lane & 7) ^ (row & 7);
        GLDS16(gbase + (size_t)row * grow_stride + c * 8,
               lds + (size_t)(i * 256 + w * 64) * 8);
    }
}

// ---------------------------------------------------------------------------
// Pass 0: invl[bh][q] = 1 / sum_k exp(s).  QBLK=128 (4 waves x 32 q-rows).
// K tile LDS-staged, double-buffered, 1 barrier/tile.
// grid (64 bh, SEQ/128) -> bid%8 = bh%8 pins each head's K to one XCD L2.
// ---------------------------------------------------------------------------
__global__ __launch_bounds__(256) void attn_pass0(
    const unsigned short* __restrict__ qb, const unsigned short* __restrict__ kb,
    float* __restrict__ invl)
{
    __shared__ unsigned short Ks[2][64 * 64];   // 8 KB each
    const int bh = blockIdx.x, b = bh >> 4, head = bh & 15;
    const int tid = threadIdx.x;
    const int w = tid >> 6, lane = tid & 63, l15 = lane & 15, lh = lane >> 4;
    const int bq = blockIdx.y * 128 + w * 32;
    const size_t rowbase = (size_t)b * SEQ;
    const unsigned short* Kh = kb + rowbase * D_MODEL + head * 64;

    bf16x8 aq[2][2];
#pragma unroll
    for (int qs = 0; qs < 2; ++qs)
#pragma unroll
        for (int kd = 0; kd < 2; ++kd)
            aq[qs][kd] = *(const bf16x8*)(qb + (rowbase + bq + qs * 16 + l15) * D_MODEL
                                          + head * 64 + kd * 32 + lh * 8);

    float rsum[2] = {0.f, 0.f};

    stage_tile64(Kh, D_MODEL, Ks[0], w, lane);
    __syncthreads();

    for (int kt = 0; kt < NT; ++kt) {
        const int cur = kt & 1;
        if (kt + 1 < NT)
            stage_tile64(Kh + (size_t)(kt + 1) * 64 * D_MODEL, D_MODEL, Ks[cur ^ 1], w, lane);

        const char* kbuf = (const char*)Ks[cur];
        f32x4 s[2][4] = {};
#pragma unroll
        for (int fj = 0; fj < 4; ++fj) {
            int key = fj * 16 + l15;
            bf16x8 kf0 = *(const bf16x8*)(kbuf + key * 128 + ((lh ^ (key & 7)) << 4));
            bf16x8 kf1 = *(const bf16x8*)(kbuf + key * 128 + (((4 + lh) ^ (key & 7)) << 4));
#pragma unroll
            for (int qs = 0; qs < 2; ++qs) {
                s[qs][fj] = __builtin_amdgcn_mfma_f32_16x16x32_bf16(kf0, aq[qs][0], s[qs][fj], 0, 0, 0);
                s[qs][fj] = __builtin_amdgcn_mfma_f32_16x16x32_bf16(kf1, aq[qs][1], s[qs][fj], 0, 0, 0);
            }
        }
#pragma unroll
        for (int qs = 0; qs < 2; ++qs)
#pragma unroll
            for (int fj = 0; fj < 4; ++fj)
                rsum[qs] += (__expf(s[qs][fj][0]) + __expf(s[qs][fj][1]))
                          + (__expf(s[qs][fj][2]) + __expf(s[qs][fj][3]));
        __syncthreads();
    }

#pragma unroll
    for (int qs = 0; qs < 2; ++qs) {
        float v = rsum[qs];
        v += __shfl_xor(v, 16, 64);
        v += __shfl_xor(v, 32, 64);
        if (lh == 0)
            invl[(size_t)bh * SEQ + bq + qs * 16 + l15] = 1.0f / v;
    }
}

// ---------------------------------------------------------------------------
// Pass 1: QK^T (recomputed), P = exp(s)*invl written to global DIRECTLY from
// registers (fp32x4, full-line write-combined in L2); PV B-operand re-layout
// via wave-private LDS Ps[32][144B]; K and V^T LDS-staged double-buffered.
// 1 barrier/tile. grid (64 bh, SEQ/128). LDS 50 KB.
// ---------------------------------------------------------------------------
__global__ __launch_bounds__(256) void attn_pass1(
    const unsigned short* __restrict__ qb, const unsigned short* __restrict__ kb,
    const unsigned short* __restrict__ vt, const float* __restrict__ invl,
    float* __restrict__ attnP, unsigned short* __restrict__ ctx)
{
    __shared__ unsigned short Ks[2][64 * 64];   // 8 KB each
    __shared__ unsigned short Vs[2][64 * 64];   // 8 KB each (V^T rows = d)
    __shared__ unsigned short Ps[4][32 * 72];   // wave-private, 144B row stride
    const int bh = blockIdx.x, b = bh >> 4, head = bh & 15;
    const int tid = threadIdx.x;
    const int w = tid >> 6, lane = tid & 63, l15 = lane & 15, lh = lane >> 4;
    const int bq = blockIdx.y * 128 + w * 32;
    const size_t rowbase = (size_t)b * SEQ;
    const unsigned short* Kh = kb + rowbase * D_MODEL + head * 64;
    const unsigned short* Vh = vt + (size_t)bh * 64 * SEQ;    // [d][s]
    char* myPs = (char*)&Ps[w][0];

    bf16x8 aq[2][2];
    float invr[2];
    float* pdst[2];
#pragma unroll
    for (int qs = 0; qs < 2; ++qs) {
#pragma unroll
        for (int kd = 0; kd < 2; ++kd)
            aq[qs][kd] = *(const bf16x8*)(qb + (rowbase + bq + qs * 16 + l15) * D_MODEL
                                          + head * 64 + kd * 32 + lh * 8);
        invr[qs] = invl[(size_t)bh * SEQ + bq + qs * 16 + l15];
        pdst[qs] = attnP + ((size_t)bh * SEQ + bq + qs * 16 + l15) * SEQ + lh * 4;
    }

    f32x4 acc[2][4] = {};   // [qset][d-block]

    stage_tile64(Kh, D_MODEL, Ks[0], w, lane);
    stage_tile64(Vh, SEQ,     Vs[0], w, lane);
    __syncthreads();

    for (int kt = 0; kt < NT; ++kt) {
        const int cur = kt & 1;
        const int bk = kt * 64;
        if (kt + 1 < NT) {
            stage_tile64(Kh + (size_t)(bk + 64) * D_MODEL, D_MODEL, Ks[cur ^ 1], w, lane);
            stage_tile64(Vh + (size_t)(bk + 64),           SEQ,     Vs[cur ^ 1], w, lane);
        }

        // ---- QK^T : S^T[key][q] ----
        const char* kbuf = (const char*)Ks[cur];
        f32x4 s[2][4] = {};
#pragma unroll
        for (int fj = 0; fj < 4; ++fj) {
            int key = fj * 16 + l15;
            bf16x8 kf0 = *(const bf16x8*)(kbuf + key * 128 + ((lh ^ (key & 7)) << 4));
            bf16x8 kf1 = *(const bf16x8*)(kbuf + key * 128 + (((4 + lh) ^ (key & 7)) << 4));
#pragma unroll
            for (int qs = 0; qs < 2; ++qs) {
                s[qs][fj] = __builtin_amdgcn_mfma_f32_16x16x32_bf16(kf0, aq[qs][0], s[qs][fj], 0, 0, 0);
                s[qs][fj] = __builtin_amdgcn_mfma_f32_16x16x32_bf16(kf1, aq[qs][1], s[qs][fj], 0, 0, 0);
            }
        }

        // ---- exp*invl: P -> global fp32 direct from regs; bf16 pack -> Ps ----
#pragma unroll
        for (int qs = 0; qs < 2; ++qs) {
#pragma unroll
            for (int fj = 0; fj < 4; ++fj) {
                float p0 = __expf(s[qs][fj][0]) * invr[qs];
                float p1 = __expf(s[qs][fj][1]) * invr[qs];
                float p2 = __expf(s[qs][fj][2]) * invr[qs];
                float p3 = __expf(s[qs][fj][3]) * invr[qs];
                float4 st = {p0, p1, p2, p3};
                *(float4*)(pdst[qs] + bk + fj * 16) = st;
                uint2 pk;
                pk.x = ((unsigned)f2bf(p1) << 16) | f2bf(p0);
                pk.y = ((unsigned)f2bf(p3) << 16) | f2bf(p2);
                *(uint2*)(myPs + (qs * 16 + l15) * 144 + fj * 32 + lh * 8) = pk;
            }
        }

        // ---- PV : O^T[d][q] += V^T[d][key] * P^T[key][q] ----
        const char* vbuf = (const char*)Vs[cur];
        bf16x8 pb[2][2];
#pragma unroll
        for (int qs = 0; qs < 2; ++qs)
#pragma unroll
            for (int ks = 0; ks < 2; ++ks)
                pb[qs][ks] = *(const bf16x8*)(myPs + (qs * 16 + l15) * 144 + ks * 64 + lh * 16);
#pragma unroll
        for (int db = 0; db < 4; ++db) {
            int d = db * 16 + l15;
            bf16x8 va0 = *(const bf16x8*)(vbuf + d * 128 + ((lh ^ (d & 7)) << 4));
            bf16x8 va1 = *(const bf16x8*)(vbuf + d * 128 + (((4 + lh) ^ (d & 7)) << 4));
#pragma unroll
            for (int qs = 0; qs < 2; ++qs) {
                acc[qs][db] = __builtin_amdgcn_mfma_f32_16x16x32_bf16(va0, pb[qs][0], acc[qs][db], 0, 0, 0);
                acc[qs][db] = __builtin_amdgcn_mfma_f32_16x16x32_bf16(va1, pb[qs][1], acc[qs][db], 0, 0, 0);
            }
        }
        __syncthreads();
    }

    // ---- ctx write: lane l15 = q, d = db*16 + lh*4 + r ----
#pragma unroll
    for (int qs = 0; qs < 2; ++qs)
#pragma unroll
        for (int db = 0; db < 4; ++db) {
            union { ushort4 u; uint2 v; } o;
            o.u.x = f2bf(acc[qs][db][0]); o.u.y = f2bf(acc[qs][db][1]);
            o.u.z = f2bf(acc[qs][db][2]); o.u.w = f2bf(acc[qs][db][3]);
            *(uint2*)&ctx[(rowbase + bq + qs * 16 + l15) * D_MODEL + head * 64 + db * 16 + lh * 4] = o.v;
        }
}

// ---------------------------------------------------------------------------
// LayerNorm over last dim (1024). 1 block/row.
// ---------------------------------------------------------------------------
__global__ __launch_bounds__(256) void layernorm_rows(
    const float* __restrict__ h, const float* __restrict__ gamma,
    const float* __restrict__ beta, float* __restrict__ out)
{
    const size_t row = blockIdx.x;
    const float* hr = h + row * D_MODEL;
    const int tid = threadIdx.x;

    float v[4];
    float s = 0.f;
#pragma unroll
    for (int i = 0; i < 4; ++i) { v[i] = hr[tid + i * 256]; s += v[i]; }
    __shared__ float red[256];
    red[tid] = s;
    __syncthreads();
    for (int st = 128; st > 0; st >>= 1) {
        if (tid < st) red[tid] += red[tid + st];
        __syncthreads();
    }
    float mean = red[0] * (1.0f / D_MODEL);
    __syncthreads();

    float vs = 0.f;
#pragma unroll
    for (int i = 0; i < 4; ++i) { float d = v[i] - mean; vs += d * d; }
    red[tid] = vs;
    __syncthreads();
    for (int st = 128; st > 0; st >>= 1) {
        if (tid < st) red[tid] += red[tid + st];
        __syncthreads();
    }
    float inv = rsqrtf(red[0] * (1.0f / D_MODEL) + EPS);

#pragma unroll
    for (int i = 0; i < 4; ++i) {
        int c = tid + i * 256;
        out[row * D_MODEL + c] = (v[i] - mean) * inv * gamma[c] + beta[c];
    }
}

// ---------------------------------------------------------------------------
extern "C" void kernel_launch(void* const* d_in, const int* in_sizes, int n_in,
                              void* d_out, int out_size, void* d_ws, size_t ws_size,
                              hipStream_t stream)
{
    const float* x     = (const float*)d_in[0];
    const float* Wq    = (const float*)d_in[1];
    const float* bq_   = (const float*)d_in[2];
    const float* Wk    = (const float*)d_in[3];
    const float* bk_   = (const float*)d_in[4];
    const float* Wv    = (const float*)d_in[5];
    const float* bv_   = (const float*)d_in[6];
    const float* Wo    = (const float*)d_in[7];
    const float* bo_   = (const float*)d_in[8];
    const float* gamma = (const float*)d_in[9];
    const float* beta  = (const float*)d_in[10];

    const size_t NX = (size_t)BATCH * SEQ * D_MODEL;   // 8388608
    const size_t NW = (size_t)D_MODEL * D_MODEL;       // 1048576

    float* out_ln = (float*)d_out;
    float* attnP  = out_ln + NX;

    unsigned short* x_bf   = (unsigned short*)d_ws;
    unsigned short* wq_bf  = x_bf + NX;
    unsigned short* wk_bf  = wq_bf + NW;
    unsigned short* wv_bf  = wk_bf + NW;
    unsigned short* wo_bf  = wv_bf + NW;
    unsigned short* q_bf   = wo_bf + NW;
    unsigned short* k_bf   = q_bf + NX;
    unsigned short* vt_bf  = k_bf + NX;                // V, stored transposed [bh][d][s]
    unsigned short* ctx_bf = vt_bf + NX;
    float* invl = (float*)(ctx_bf + NX);               // 64*2048 f32
    float* hbuf = (float*)q_bf;                        // reuse q+k region (f32 NX)

    const int M = BATCH * SEQ;   // 8192

    cvt_all<<<12288, 256, 0, stream>>>(x, Wq, Wk, Wv, Wo,
                                       x_bf, wq_bf, wk_bf, wv_bf, wo_bf);

    gemm_qkv<<<dim3(24, M / 128), 256, 0, stream>>>(
        x_bf, wq_bf, wk_bf, wv_bf, bq_, bk_, bv_, q_bf, k_bf, vt_bf);

    attn_pass0<<<dim3(BATCH * N_HEADS, SEQ / 128), 256, 0, stream>>>(q_bf, k_bf, invl);

    attn_pass1<<<dim3(BATCH * N_HEADS, SEQ / 128), 256, 0, stream>>>(
        q_bf, k_bf, vt_bf, invl, attnP, ctx_bf);

    gemm_out<<<dim3(D_MODEL / 128, M / 128), 256, 0, stream>>>(
        ctx_bf, wo_bf, bo_, x, hbuf);

    layernorm_rows<<<M, 256, 0, stream>>>(hbuf, gamma, beta, out_ln);
}

// Round 10
// 555.441 us; speedup vs baseline: 1.0188x; 1.0188x over previous
//
#include <hip/hip_runtime.h>
#include <math.h>

#define D_MODEL 1024
#define N_HEADS 16
#define D_K     64
#define SEQ     2048
#define BATCH   4
#define EPS     1e-5f
#define NT      (SEQ / 64)   // 32 key-tiles

typedef __attribute__((ext_vector_type(8))) short bf16x8;
typedef __attribute__((ext_vector_type(4))) float f32x4;

__device__ __forceinline__ unsigned short f2bf(float f) {
    unsigned u = __float_as_uint(f);
    u += 0x7fff + ((u >> 16) & 1);   // RNE
    return (unsigned short)(u >> 16);
}

#define GLDS16(g, l) __builtin_amdgcn_global_load_lds( \
    (const __attribute__((address_space(1))) void*)(g), \
    (__attribute__((address_space(3))) void*)(l), 16, 0, 0)

// ---------------------------------------------------------------------------
// One-shot f32 -> bf16 convert of x + 4 weight matrices (region table).
// ---------------------------------------------------------------------------
__global__ __launch_bounds__(256) void cvt_all(
    const float* __restrict__ x,
    const float* __restrict__ Wq, const float* __restrict__ Wk,
    const float* __restrict__ Wv, const float* __restrict__ Wo,
    unsigned short* __restrict__ xb,
    unsigned short* __restrict__ wqb, unsigned short* __restrict__ wkb,
    unsigned short* __restrict__ wvb, unsigned short* __restrict__ wob)
{
    size_t i4 = (size_t)blockIdx.x * 256 + threadIdx.x;
    const float* src; unsigned short* dst; size_t off;
    if (i4 < 2097152) { src = x; dst = xb; off = i4; }
    else {
        size_t j = i4 - 2097152;
        int wsel = (int)(j >> 18);          // 0..3
        off = j & 262143;
        switch (wsel) {
            case 0:  src = Wq; dst = wqb; break;
            case 1:  src = Wk; dst = wkb; break;
            case 2:  src = Wv; dst = wvb; break;
            default: src = Wo; dst = wob; break;
        }
    }
    float4 f = ((const float4*)src)[off];
    union { ushort4 u; uint2 v; } o;
    o.u.x = f2bf(f.x); o.u.y = f2bf(f.y); o.u.z = f2bf(f.z); o.u.w = f2bf(f.w);
    ((uint2*)dst)[off] = o.v;
}

// ---------------------------------------------------------------------------
// Fused QKV projection: Ot = x @ Wt^T + bt (bf16 out); Q scaled by 0.125.
// which==2 (V) writes DIRECTLY TRANSPOSED: vt[bh][d][s] (s-contig 4/lane).
// Single-buffered (proven r8 form: 8 blocks/CU beats dbuf at 5 blocks/CU).
// grid.x = 24 : [which 0..2][bn 0..7] ; grid.y = 64. 128x128 tile, BK=32.
// ---------------------------------------------------------------------------
__global__ __launch_bounds__(256) void gemm_qkv(
    const unsigned short* __restrict__ A,
    const unsigned short* __restrict__ Bq, const unsigned short* __restrict__ Bk,
    const unsigned short* __restrict__ Bv,
    const float* __restrict__ biq, const float* __restrict__ bik,
    const float* __restrict__ biv,
    unsigned short* __restrict__ Oq, unsigned short* __restrict__ Ok,
    unsigned short* __restrict__ Vt)
{
    const int which = blockIdx.x >> 3;
    const unsigned short* B = which == 0 ? Bq : (which == 1 ? Bk : Bv);
    const float* bias        = which == 0 ? biq : (which == 1 ? bik : biv);
    const float scale        = which == 0 ? 0.125f : 1.0f;

    __shared__ unsigned short As[128 * 32];
    __shared__ unsigned short Bs[128 * 32];
    const int tid = threadIdx.x;
    const int w = tid >> 6, lane = tid & 63;
    const int l15 = lane & 15, lh = lane >> 4;
    const int wm = w >> 1, wn = w & 1;
    const int bm = blockIdx.y * 128, bn = (blockIdx.x & 7) * 128;
    const int K = D_MODEL, N = D_MODEL;

    const int srow = lane >> 2;
    const int skk  = (lane & 3) * 8;

    f32x4 acc[4][4] = {};

    for (int k0 = 0; k0 < K; k0 += 32) {
#pragma unroll
        for (int cc = 0; cc < 2; ++cc) {
            int chunk = w * 2 + cc;
            int row = chunk * 16 + srow;
            GLDS16(A + (size_t)(bm + row) * K + k0 + skk, As + chunk * 512);
            GLDS16(B + (size_t)(bn + row) * K + k0 + skk, Bs + chunk * 512);
        }
        __syncthreads();
        bf16x8 af[4], bfr[4];
#pragma unroll
        for (int mi = 0; mi < 4; ++mi)
            af[mi] = *(const bf16x8*)&As[(wm * 64 + mi * 16 + l15) * 32 + lh * 8];
#pragma unroll
        for (int nj = 0; nj < 4; ++nj)
            bfr[nj] = *(const bf16x8*)&Bs[(wn * 64 + nj * 16 + l15) * 32 + lh * 8];
#pragma unroll
        for (int mi = 0; mi < 4; ++mi)
#pragma unroll
            for (int nj = 0; nj < 4; ++nj)
                acc[mi][nj] = __builtin_amdgcn_mfma_f32_16x16x32_bf16(
                    af[mi], bfr[nj], acc[mi][nj], 0, 0, 0);
        __syncthreads();
    }

    if (which == 2) {
        // transposed V write: vt[((b*16+head)*64 + d)*SEQ + s], 4 bf16 along s
#pragma unroll
        for (int mi = 0; mi < 4; ++mi) {
#pragma unroll
            for (int nj = 0; nj < 4; ++nj) {
                int col = bn + wn * 64 + nj * 16 + l15;
                int head = col >> 6, d = col & 63;
                float bv = bias[col];
                int row = bm + wm * 64 + mi * 16 + lh * 4;
                int b = row >> 11, s = row & 2047;
                union { ushort4 u; uint2 v; } o;
                o.u.x = f2bf(acc[mi][nj][0] + bv);
                o.u.y = f2bf(acc[mi][nj][1] + bv);
                o.u.z = f2bf(acc[mi][nj][2] + bv);
                o.u.w = f2bf(acc[mi][nj][3] + bv);
                *(uint2*)&Vt[(((size_t)b * 16 + head) * 64 + d) * SEQ + s] = o.v;
            }
        }
    } else {
        unsigned short* O = which == 0 ? Oq : Ok;
#pragma unroll
        for (int mi = 0; mi < 4; ++mi) {
#pragma unroll
            for (int nj = 0; nj < 4; ++nj) {
                int col = bn + wn * 64 + nj * 16 + l15;
                float bv = bias[col];
#pragma unroll
                for (int r = 0; r < 4; ++r) {
                    int row = bm + wm * 64 + mi * 16 + lh * 4 + r;
                    O[(size_t)row * N + col] = f2bf((acc[mi][nj][r] + bv) * scale);
                }
            }
        }
    }
}

// ---------------------------------------------------------------------------
// Output projection: C = ctx @ Wo^T + bo + residual (fp32 out). 128x128, BK=32.
// Single-buffered (r8 form).
// ---------------------------------------------------------------------------
__global__ __launch_bounds__(256) void gemm_out(
    const unsigned short* __restrict__ A, const unsigned short* __restrict__ B,
    const float* __restrict__ bias, const float* __restrict__ res,
    float* __restrict__ C)
{
    __shared__ unsigned short As[128 * 32];
    __shared__ unsigned short Bs[128 * 32];
    const int tid = threadIdx.x;
    const int w = tid >> 6, lane = tid & 63;
    const int l15 = lane & 15, lh = lane >> 4;
    const int wm = w >> 1, wn = w & 1;
    const int bm = blockIdx.y * 128, bn = blockIdx.x * 128;
    const int K = D_MODEL, N = D_MODEL;

    const int srow = lane >> 2;
    const int skk  = (lane & 3) * 8;

    f32x4 acc[4][4] = {};

    for (int k0 = 0; k0 < K; k0 += 32) {
#pragma unroll
        for (int cc = 0; cc < 2; ++cc) {
            int chunk = w * 2 + cc;
            int row = chunk * 16 + srow;
            GLDS16(A + (size_t)(bm + row) * K + k0 + skk, As + chunk * 512);
            GLDS16(B + (size_t)(bn + row) * K + k0 + skk, Bs + chunk * 512);
        }
        __syncthreads();
        bf16x8 af[4], bfr[4];
#pragma unroll
        for (int mi = 0; mi < 4; ++mi)
            af[mi] = *(const bf16x8*)&As[(wm * 64 + mi * 16 + l15) * 32 + lh * 8];
#pragma unroll
        for (int nj = 0; nj < 4; ++nj)
            bfr[nj] = *(const bf16x8*)&Bs[(wn * 64 + nj * 16 + l15) * 32 + lh * 8];
#pragma unroll
        for (int mi = 0; mi < 4; ++mi)
#pragma unroll
            for (int nj = 0; nj < 4; ++nj)
                acc[mi][nj] = __builtin_amdgcn_mfma_f32_16x16x32_bf16(
                    af[mi], bfr[nj], acc[mi][nj], 0, 0, 0);
        __syncthreads();
    }

#pragma unroll
    for (int mi = 0; mi < 4; ++mi) {
#pragma unroll
        for (int nj = 0; nj < 4; ++nj) {
            int col = bn + wn * 64 + nj * 16 + l15;
            float bv = bias[col];
#pragma unroll
            for (int r = 0; r < 4; ++r) {
                int row = bm + wm * 64 + mi * 16 + lh * 4 + r;
                C[(size_t)row * N + col] = acc[mi][nj][r] + bv + res[(size_t)row * N + col];
            }
        }
    }
}

// ---------------------------------------------------------------------------
// Staging helper for 512-thread blocks: stage a 64-row x 128B tile into LDS.
// Each of the 512 threads issues exactly 1 global_load_lds (16B).
// Linear LDS dest (base + lane*16 within each wave), chunk-swizzled global
// source: lds chunk cs <- global chunk cs ^ (row&7). Read side XORs the same
// involution -> conflict-free ds_read_b128.
// ---------------------------------------------------------------------------
__device__ __forceinline__ void stage_tile64_w8(
    const unsigned short* __restrict__ gbase, size_t grow_stride,
    unsigned short* lds, int tid)
{
    int row = tid >> 3, cs = tid & 7;
    int c = cs ^ (row & 7);
    GLDS16(gbase + (size_t)row * grow_stride + c * 8, lds + (size_t)tid * 8);
}

// ---------------------------------------------------------------------------
// Pass 0: invl[bh][q] = 1 / sum_k exp(s).  QBLK=256 (8 waves x 32 q-rows),
// 512 threads. K tile LDS-staged (shared by 8 waves), double-buffered,
// 1 barrier/tile. grid (64 bh, SEQ/256=8) = 512 blocks -> all co-resident.
// ---------------------------------------------------------------------------
__global__ __launch_bounds__(512) void attn_pass0(
    const unsigned short* __restrict__ qb, const unsigned short* __restrict__ kb,
    float* __restrict__ invl)
{
    __shared__ unsigned short Ks[2][64 * 64];   // 8 KB each
    const int bh = blockIdx.x, b = bh >> 4, head = bh & 15;
    const int tid = threadIdx.x;
    const int w = tid >> 6, lane = tid & 63, l15 = lane & 15, lh = lane >> 4;
    const int bq = blockIdx.y * 256 + w * 32;
    const size_t rowbase = (size_t)b * SEQ;
    const unsigned short* Kh = kb + rowbase * D_MODEL + head * 64;

    bf16x8 aq[2][2];
#pragma unroll
    for (int qs = 0; qs < 2; ++qs)
#pragma unroll
        for (int kd = 0; kd < 2; ++kd)
            aq[qs][kd] = *(const bf16x8*)(qb + (rowbase + bq + qs * 16 + l15) * D_MODEL
                                          + head * 64 + kd * 32 + lh * 8);

    float rsum[2] = {0.f, 0.f};

    stage_tile64_w8(Kh, D_MODEL, Ks[0], tid);
    __syncthreads();

    for (int kt = 0; kt < NT; ++kt) {
        const int cur = kt & 1;
        if (kt + 1 < NT)
            stage_tile64_w8(Kh + (size_t)(kt + 1) * 64 * D_MODEL, D_MODEL, Ks[cur ^ 1], tid);

        const char* kbuf = (const char*)Ks[cur];
        f32x4 s[2][4] = {};
#pragma unroll
        for (int fj = 0; fj < 4; ++fj) {
            int key = fj * 16 + l15;
            bf16x8 kf0 = *(const bf16x8*)(kbuf + key * 128 + ((lh ^ (key & 7)) << 4));
            bf16x8 kf1 = *(const bf16x8*)(kbuf + key * 128 + (((4 + lh) ^ (key & 7)) << 4));
#pragma unroll
            for (int qs = 0; qs < 2; ++qs) {
                s[qs][fj] = __builtin_amdgcn_mfma_f32_16x16x32_bf16(kf0, aq[qs][0], s[qs][fj], 0, 0, 0);
                s[qs][fj] = __builtin_amdgcn_mfma_f32_16x16x32_bf16(kf1, aq[qs][1], s[qs][fj], 0, 0, 0);
            }
        }
#pragma unroll
        for (int qs = 0; qs < 2; ++qs)
#pragma unroll
            for (int fj = 0; fj < 4; ++fj)
                rsum[qs] += (__expf(s[qs][fj][0]) + __expf(s[qs][fj][1]))
                          + (__expf(s[qs][fj][2]) + __expf(s[qs][fj][3]));
        __syncthreads();
    }

#pragma unroll
    for (int qs = 0; qs < 2; ++qs) {
        float v = rsum[qs];
        v += __shfl_xor(v, 16, 64);
        v += __shfl_xor(v, 32, 64);
        if (lh == 0)
            invl[(size_t)bh * SEQ + bq + qs * 16 + l15] = 1.0f / v;
    }
}

// ---------------------------------------------------------------------------
// Pass 1: QK^T (recomputed), P = exp(s)*invl written to global DIRECTLY from
// registers (fp32x4, L2 write-combined); PV B-operand re-layout via
// wave-private LDS Ps[8][32][144B]; K and V^T LDS-staged double-buffered
// (shared by 8 waves). 1 barrier/tile. QBLK=256, 512 threads.
// grid (64 bh, 8) = 512 blocks, 68 KB LDS -> 2 blocks/CU, ALL co-resident.
// ---------------------------------------------------------------------------
__global__ __launch_bounds__(512) void attn_pass1(
    const unsigned short* __restrict__ qb, const unsigned short* __restrict__ kb,
    const unsigned short* __restrict__ vt, const float* __restrict__ invl,
    float* __restrict__ attnP, unsigned short* __restrict__ ctx)
{
    __shared__ unsigned short Ks[2][64 * 64];   // 8 KB each
    __shared__ unsigned short Vs[2][64 * 64];   // 8 KB each (V^T rows = d)
    __shared__ unsigned short Ps[8][32 * 72];   // wave-private, 144B row stride
    const int bh = blockIdx.x, b = bh >> 4, head = bh & 15;
    const int tid = threadIdx.x;
    const int w = tid >> 6, lane = tid & 63, l15 = lane & 15, lh = lane >> 4;
    const int bq = blockIdx.y * 256 + w * 32;
    const size_t rowbase = (size_t)b * SEQ;
    const unsigned short* Kh = kb + rowbase * D_MODEL + head * 64;
    const unsigned short* Vh = vt + (size_t)bh * 64 * SEQ;    // [d][s]
    char* myPs = (char*)&Ps[w][0];

    bf16x8 aq[2][2];
    float invr[2];
    float* pdst[2];
#pragma unroll
    for (int qs = 0; qs < 2; ++qs) {
#pragma unroll
        for (int kd = 0; kd < 2; ++kd)
            aq[qs][kd] = *(const bf16x8*)(qb + (rowbase + bq + qs * 16 + l15) * D_MODEL
                                          + head * 64 + kd * 32 + lh * 8);
        invr[qs] = invl[(size_t)bh * SEQ + bq + qs * 16 + l15];
        pdst[qs] = attnP + ((size_t)bh * SEQ + bq + qs * 16 + l15) * SEQ + lh * 4;
    }

    f32x4 acc[2][4] = {};   // [qset][d-block]

    stage_tile64_w8(Kh, D_MODEL, Ks[0], tid);
    stage_tile64_w8(Vh, SEQ,     Vs[0], tid);
    __syncthreads();

    for (int kt = 0; kt < NT; ++kt) {
        const int cur = kt & 1;
        const int bk = kt * 64;
        if (kt + 1 < NT) {
            stage_tile64_w8(Kh + (size_t)(bk + 64) * D_MODEL, D_MODEL, Ks[cur ^ 1], tid);
            stage_tile64_w8(Vh + (size_t)(bk + 64),           SEQ,     Vs[cur ^ 1], tid);
        }

        // ---- QK^T : S^T[key][q] ----
        const char* kbuf = (const char*)Ks[cur];
        f32x4 s[2][4] = {};
#pragma unroll
        for (int fj = 0; fj < 4; ++fj) {
            int key = fj * 16 + l15;
            bf16x8 kf0 = *(const bf16x8*)(kbuf + key * 128 + ((lh ^ (key & 7)) << 4));
            bf16x8 kf1 = *(const bf16x8*)(kbuf + key * 128 + (((4 + lh) ^ (key & 7)) << 4));
#pragma unroll
            for (int qs = 0; qs < 2; ++qs) {
                s[qs][fj] = __builtin_amdgcn_mfma_f32_16x16x32_bf16(kf0, aq[qs][0], s[qs][fj], 0, 0, 0);
                s[qs][fj] = __builtin_amdgcn_mfma_f32_16x16x32_bf16(kf1, aq[qs][1], s[qs][fj], 0, 0, 0);
            }
        }

        // ---- exp*invl: P -> global fp32 direct from regs; bf16 pack -> Ps ----
#pragma unroll
        for (int qs = 0; qs < 2; ++qs) {
#pragma unroll
            for (int fj = 0; fj < 4; ++fj) {
                float p0 = __expf(s[qs][fj][0]) * invr[qs];
                float p1 = __expf(s[qs][fj][1]) * invr[qs];
                float p2 = __expf(s[qs][fj][2]) * invr[qs];
                float p3 = __expf(s[qs][fj][3]) * invr[qs];
                float4 st = {p0, p1, p2, p3};
                *(float4*)(pdst[qs] + bk + fj * 16) = st;
                uint2 pk;
                pk.x = ((unsigned)f2bf(p1) << 16) | f2bf(p0);
                pk.y = ((unsigned)f2bf(p3) << 16) | f2bf(p2);
                *(uint2*)(myPs + (qs * 16 + l15) * 144 + fj * 32 + lh * 8) = pk;
            }
        }

        // ---- PV : O^T[d][q] += V^T[d][key] * P^T[key][q] ----
        const char* vbuf = (const char*)Vs[cur];
        bf16x8 pb[2][2];
#pragma unroll
        for (int qs = 0; qs < 2; ++qs)
#pragma unroll
            for (int ks = 0; ks < 2; ++ks)
                pb[qs][ks] = *(const bf16x8*)(myPs + (qs * 16 + l15) * 144 + ks * 64 + lh * 16);
#pragma unroll
        for (int db = 0; db < 4; ++db) {
            int d = db * 16 + l15;
            bf16x8 va0 = *(const bf16x8*)(vbuf + d * 128 + ((lh ^ (d & 7)) << 4));
            bf16x8 va1 = *(const bf16x8*)(vbuf + d * 128 + (((4 + lh) ^ (d & 7)) << 4));
#pragma unroll
            for (int qs = 0; qs < 2; ++qs) {
                acc[qs][db] = __builtin_amdgcn_mfma_f32_16x16x32_bf16(va0, pb[qs][0], acc[qs][db], 0, 0, 0);
                acc[qs][db] = __builtin_amdgcn_mfma_f32_16x16x32_bf16(va1, pb[qs][1], acc[qs][db], 0, 0, 0);
            }
        }
        __syncthreads();
    }

    // ---- ctx write: lane l15 = q, d = db*16 + lh*4 + r ----
#pragma unroll
    for (int qs = 0; qs < 2; ++qs)
#pragma unroll
        for (int db = 0; db < 4; ++db) {
            union { ushort4 u; uint2 v; } o;
            o.u.x = f2bf(acc[qs][db][0]); o.u.y = f2bf(acc[qs][db][1]);
            o.u.z = f2bf(acc[qs][db][2]); o.u.w = f2bf(acc[qs][db][3]);
            *(uint2*)&ctx[(rowbase + bq + qs * 16 + l15) * D_MODEL + head * 64 + db * 16 + lh * 4] = o.v;
        }
}

// ---------------------------------------------------------------------------
// LayerNorm over last dim (1024). 1 block/row.
// ---------------------------------------------------------------------------
__global__ __launch_bounds__(256) void layernorm_rows(
    const float* __restrict__ h, const float* __restrict__ gamma,
    const float* __restrict__ beta, float* __restrict__ out)
{
    const size_t row = blockIdx.x;
    const float* hr = h + row * D_MODEL;
    const int tid = threadIdx.x;

    float v[4];
    float s = 0.f;
#pragma unroll
    for (int i = 0; i < 4; ++i) { v[i] = hr[tid + i * 256]; s += v[i]; }
    __shared__ float red[256];
    red[tid] = s;
    __syncthreads();
    for (int st = 128; st > 0; st >>= 1) {
        if (tid < st) red[tid] += red[tid + st];
        __syncthreads();
    }
    float mean = red[0] * (1.0f / D_MODEL);
    __syncthreads();

    float vs = 0.f;
#pragma unroll
    for (int i = 0; i < 4; ++i) { float d = v[i] - mean; vs += d * d; }
    red[tid] = vs;
    __syncthreads();
    for (int st = 128; st > 0; st >>= 1) {
        if (tid < st) red[tid] += red[tid + st];
        __syncthreads();
    }
    float inv = rsqrtf(red[0] * (1.0f / D_MODEL) + EPS);

#pragma unroll
    for (int i = 0; i < 4; ++i) {
        int c = tid + i * 256;
        out[row * D_MODEL + c] = (v[i] - mean) * inv * gamma[c] + beta[c];
    }
}

// ---------------------------------------------------------------------------
extern "C" void kernel_launch(void* const* d_in, const int* in_sizes, int n_in,
                              void* d_out, int out_size, void* d_ws, size_t ws_size,
                              hipStream_t stream)
{
    const float* x     = (const float*)d_in[0];
    const float* Wq    = (const float*)d_in[1];
    const float* bq_   = (const float*)d_in[2];
    const float* Wk    = (const float*)d_in[3];
    const float* bk_   = (const float*)d_in[4];
    const float* Wv    = (const float*)d_in[5];
    const float* bv_   = (const float*)d_in[6];
    const float* Wo    = (const float*)d_in[7];
    const float* bo_   = (const float*)d_in[8];
    const float* gamma = (const float*)d_in[9];
    const float* beta  = (const float*)d_in[10];

    const size_t NX = (size_t)BATCH * SEQ * D_MODEL;   // 8388608
    const size_t NW = (size_t)D_MODEL * D_MODEL;       // 1048576

    float* out_ln = (float*)d_out;
    float* attnP  = out_ln + NX;

    unsigned short* x_bf   = (unsigned short*)d_ws;
    unsigned short* wq_bf  = x_bf + NX;
    unsigned short* wk_bf  = wq_bf + NW;
    unsigned short* wv_bf  = wk_bf + NW;
    unsigned short* wo_bf  = wv_bf + NW;
    unsigned short* q_bf   = wo_bf + NW;
    unsigned short* k_bf   = q_bf + NX;
    unsigned short* vt_bf  = k_bf + NX;                // V, stored transposed [bh][d][s]
    unsigned short* ctx_bf = vt_bf + NX;
    float* invl = (float*)(ctx_bf + NX);               // 64*2048 f32
    float* hbuf = (float*)q_bf;                        // reuse q+k region (f32 NX)

    const int M = BATCH * SEQ;   // 8192

    cvt_all<<<12288, 256, 0, stream>>>(x, Wq, Wk, Wv, Wo,
                                       x_bf, wq_bf, wk_bf, wv_bf, wo_bf);

    gemm_qkv<<<dim3(24, M / 128), 256, 0, stream>>>(
        x_bf, wq_bf, wk_bf, wv_bf, bq_, bk_, bv_, q_bf, k_bf, vt_bf);

    attn_pass0<<<dim3(BATCH * N_HEADS, SEQ / 256), 512, 0, stream>>>(q_bf, k_bf, invl);

    attn_pass1<<<dim3(BATCH * N_HEADS, SEQ / 256), 512, 0, stream>>>(
        q_bf, k_bf, vt_bf, invl, attnP, ctx_bf);

    gemm_out<<<dim3(D_MODEL / 128, M / 128), 256, 0, stream>>>(
        ctx_bf, wo_bf, bo_, x, hbuf);

    layernorm_rows<<<M, 256, 0, stream>>>(hbuf, gamma, beta, out_ln);
}

// Round 11
// 535.541 us; speedup vs baseline: 1.0567x; 1.0372x over previous
//
#include <hip/hip_runtime.h>
#include <math.h>

#define D_MODEL 1024
#define N_HEADS 16
#define D_K     64
#define SEQ     2048
#define BATCH   4
#define EPS     1e-5f
#define NT      (SEQ / 64)   // 32 key-tiles

typedef __attribute__((ext_vector_type(8))) short bf16x8;
typedef __attribute__((ext_vector_type(4))) float f32x4;

__device__ __forceinline__ unsigned short f2bf(float f) {
    unsigned u = __float_as_uint(f);
    u += 0x7fff + ((u >> 16) & 1);   // RNE
    return (unsigned short)(u >> 16);
}

#define GLDS16(g, l) __builtin_amdgcn_global_load_lds( \
    (const __attribute__((address_space(1))) void*)(g), \
    (__attribute__((address_space(3))) void*)(l), 16, 0, 0)

// ---------------------------------------------------------------------------
// One-shot f32 -> bf16 convert of x + 4 weight matrices (region table).
// ---------------------------------------------------------------------------
__global__ __launch_bounds__(256) void cvt_all(
    const float* __restrict__ x,
    const float* __restrict__ Wq, const float* __restrict__ Wk,
    const float* __restrict__ Wv, const float* __restrict__ Wo,
    unsigned short* __restrict__ xb,
    unsigned short* __restrict__ wqb, unsigned short* __restrict__ wkb,
    unsigned short* __restrict__ wvb, unsigned short* __restrict__ wob)
{
    size_t i4 = (size_t)blockIdx.x * 256 + threadIdx.x;
    const float* src; unsigned short* dst; size_t off;
    if (i4 < 2097152) { src = x; dst = xb; off = i4; }
    else {
        size_t j = i4 - 2097152;
        int wsel = (int)(j >> 18);          // 0..3
        off = j & 262143;
        switch (wsel) {
            case 0:  src = Wq; dst = wqb; break;
            case 1:  src = Wk; dst = wkb; break;
            case 2:  src = Wv; dst = wvb; break;
            default: src = Wo; dst = wob; break;
        }
    }
    float4 f = ((const float4*)src)[off];
    union { ushort4 u; uint2 v; } o;
    o.u.x = f2bf(f.x); o.u.y = f2bf(f.y); o.u.z = f2bf(f.z); o.u.w = f2bf(f.w);
    ((uint2*)dst)[off] = o.v;
}

// ---------------------------------------------------------------------------
// Fused QKV projection: Ot = x @ Wt^T + bt (bf16 out); Q scaled by 0.125.
// which==2 (V) writes DIRECTLY TRANSPOSED: vt[bh][d][s] (s-contig 4/lane).
// Single-buffered (8 blocks/CU beats explicit dbuf at 5 blocks/CU — r9).
// grid.x = 24 : [which 0..2][bn 0..7] ; grid.y = 64. 128x128 tile, BK=32.
// ---------------------------------------------------------------------------
__global__ __launch_bounds__(256) void gemm_qkv(
    const unsigned short* __restrict__ A,
    const unsigned short* __restrict__ Bq, const unsigned short* __restrict__ Bk,
    const unsigned short* __restrict__ Bv,
    const float* __restrict__ biq, const float* __restrict__ bik,
    const float* __restrict__ biv,
    unsigned short* __restrict__ Oq, unsigned short* __restrict__ Ok,
    unsigned short* __restrict__ Vt)
{
    const int which = blockIdx.x >> 3;
    const unsigned short* B = which == 0 ? Bq : (which == 1 ? Bk : Bv);
    const float* bias        = which == 0 ? biq : (which == 1 ? bik : biv);
    const float scale        = which == 0 ? 0.125f : 1.0f;

    __shared__ unsigned short As[128 * 32];
    __shared__ unsigned short Bs[128 * 32];
    const int tid = threadIdx.x;
    const int w = tid >> 6, lane = tid & 63;
    const int l15 = lane & 15, lh = lane >> 4;
    const int wm = w >> 1, wn = w & 1;
    const int bm = blockIdx.y * 128, bn = (blockIdx.x & 7) * 128;
    const int K = D_MODEL, N = D_MODEL;

    const int srow = lane >> 2;
    const int skk  = (lane & 3) * 8;

    f32x4 acc[4][4] = {};

    for (int k0 = 0; k0 < K; k0 += 32) {
#pragma unroll
        for (int cc = 0; cc < 2; ++cc) {
            int chunk = w * 2 + cc;
            int row = chunk * 16 + srow;
            GLDS16(A + (size_t)(bm + row) * K + k0 + skk, As + chunk * 512);
            GLDS16(B + (size_t)(bn + row) * K + k0 + skk, Bs + chunk * 512);
        }
        __syncthreads();
        bf16x8 af[4], bfr[4];
#pragma unroll
        for (int mi = 0; mi < 4; ++mi)
            af[mi] = *(const bf16x8*)&As[(wm * 64 + mi * 16 + l15) * 32 + lh * 8];
#pragma unroll
        for (int nj = 0; nj < 4; ++nj)
            bfr[nj] = *(const bf16x8*)&Bs[(wn * 64 + nj * 16 + l15) * 32 + lh * 8];
#pragma unroll
        for (int mi = 0; mi < 4; ++mi)
#pragma unroll
            for (int nj = 0; nj < 4; ++nj)
                acc[mi][nj] = __builtin_amdgcn_mfma_f32_16x16x32_bf16(
                    af[mi], bfr[nj], acc[mi][nj], 0, 0, 0);
        __syncthreads();
    }

    if (which == 2) {
        // transposed V write: vt[((b*16+head)*64 + d)*SEQ + s], 4 bf16 along s
#pragma unroll
        for (int mi = 0; mi < 4; ++mi) {
#pragma unroll
            for (int nj = 0; nj < 4; ++nj) {
                int col = bn + wn * 64 + nj * 16 + l15;
                int head = col >> 6, d = col & 63;
                float bv = bias[col];
                int row = bm + wm * 64 + mi * 16 + lh * 4;
                int b = row >> 11, s = row & 2047;
                union { ushort4 u; uint2 v; } o;
                o.u.x = f2bf(acc[mi][nj][0] + bv);
                o.u.y = f2bf(acc[mi][nj][1] + bv);
                o.u.z = f2bf(acc[mi][nj][2] + bv);
                o.u.w = f2bf(acc[mi][nj][3] + bv);
                *(uint2*)&Vt[(((size_t)b * 16 + head) * 64 + d) * SEQ + s] = o.v;
            }
        }
    } else {
        unsigned short* O = which == 0 ? Oq : Ok;
#pragma unroll
        for (int mi = 0; mi < 4; ++mi) {
#pragma unroll
            for (int nj = 0; nj < 4; ++nj) {
                int col = bn + wn * 64 + nj * 16 + l15;
                float bv = bias[col];
#pragma unroll
                for (int r = 0; r < 4; ++r) {
                    int row = bm + wm * 64 + mi * 16 + lh * 4 + r;
                    O[(size_t)row * N + col] = f2bf((acc[mi][nj][r] + bv) * scale);
                }
            }
        }
    }
}

// ---------------------------------------------------------------------------
// Output projection: C = ctx @ Wo^T + bo + residual (fp32 out). 128x128, BK=32.
// Single-buffered (r8 form).
// ---------------------------------------------------------------------------
__global__ __launch_bounds__(256) void gemm_out(
    const unsigned short* __restrict__ A, const unsigned short* __restrict__ B,
    const float* __restrict__ bias, const float* __restrict__ res,
    float* __restrict__ C)
{
    __shared__ unsigned short As[128 * 32];
    __shared__ unsigned short Bs[128 * 32];
    const int tid = threadIdx.x;
    const int w = tid >> 6, lane = tid & 63;
    const int l15 = lane & 15, lh = lane >> 4;
    const int wm = w >> 1, wn = w & 1;
    const int bm = blockIdx.y * 128, bn = blockIdx.x * 128;
    const int K = D_MODEL, N = D_MODEL;

    const int srow = lane >> 2;
    const int skk  = (lane & 3) * 8;

    f32x4 acc[4][4] = {};

    for (int k0 = 0; k0 < K; k0 += 32) {
#pragma unroll
        for (int cc = 0; cc < 2; ++cc) {
            int chunk = w * 2 + cc;
            int row = chunk * 16 + srow;
            GLDS16(A + (size_t)(bm + row) * K + k0 + skk, As + chunk * 512);
            GLDS16(B + (size_t)(bn + row) * K + k0 + skk, Bs + chunk * 512);
        }
        __syncthreads();
        bf16x8 af[4], bfr[4];
#pragma unroll
        for (int mi = 0; mi < 4; ++mi)
            af[mi] = *(const bf16x8*)&As[(wm * 64 + mi * 16 + l15) * 32 + lh * 8];
#pragma unroll
        for (int nj = 0; nj < 4; ++nj)
            bfr[nj] = *(const bf16x8*)&Bs[(wn * 64 + nj * 16 + l15) * 32 + lh * 8];
#pragma unroll
        for (int mi = 0; mi < 4; ++mi)
#pragma unroll
            for (int nj = 0; nj < 4; ++nj)
                acc[mi][nj] = __builtin_amdgcn_mfma_f32_16x16x32_bf16(
                    af[mi], bfr[nj], acc[mi][nj], 0, 0, 0);
        __syncthreads();
    }

#pragma unroll
    for (int mi = 0; mi < 4; ++mi) {
#pragma unroll
        for (int nj = 0; nj < 4; ++nj) {
            int col = bn + wn * 64 + nj * 16 + l15;
            float bv = bias[col];
#pragma unroll
            for (int r = 0; r < 4; ++r) {
                int row = bm + wm * 64 + mi * 16 + lh * 4 + r;
                C[(size_t)row * N + col] = acc[mi][nj][r] + bv + res[(size_t)row * N + col];
            }
        }
    }
}

// ---------------------------------------------------------------------------
// Staging helper (4-wave): stage a 64-row x 128B tile into LDS (linear dest,
// chunk-swizzled global source: lds chunk cs <- global chunk cs ^ (row&7)).
// Read side XORs the same involution -> conflict-free ds_read_b128.
// Issues exactly 2 global_load_lds per thread.
// ---------------------------------------------------------------------------
__device__ __forceinline__ void stage_tile64(
    const unsigned short* __restrict__ gbase, size_t grow_stride,
    unsigned short* lds, int w, int lane)
{
#pragma unroll
    for (int i = 0; i < 2; ++i) {
        int row = i * 32 + w * 8 + (lane >> 3);
        int c   = (lane & 7) ^ (row & 7);
        GLDS16(gbase + (size_t)row * grow_stride + c * 8,
               lds + (size_t)(i * 256 + w * 64) * 8);
    }
}

// ---------------------------------------------------------------------------
// Pass 0: invl[bh][q] = 1 / sum_k exp(s).  QBLK=128 (4 waves x 32 q-rows).
// K tile LDS-staged, double-buffered, 1 barrier/tile. (r8 form)
// grid (64 bh, SEQ/128) -> bid%8 = bh%8 pins each head's K to one XCD L2.
// ---------------------------------------------------------------------------
__global__ __launch_bounds__(256) void attn_pass0(
    const unsigned short* __restrict__ qb, const unsigned short* __restrict__ kb,
    float* __restrict__ invl)
{
    __shared__ unsigned short Ks[2][64 * 64];   // 8 KB each
    const int bh = blockIdx.x, b = bh >> 4, head = bh & 15;
    const int tid = threadIdx.x;
    const int w = tid >> 6, lane = tid & 63, l15 = lane & 15, lh = lane >> 4;
    const int bq = blockIdx.y * 128 + w * 32;
    const size_t rowbase = (size_t)b * SEQ;
    const unsigned short* Kh = kb + rowbase * D_MODEL + head * 64;

    bf16x8 aq[2][2];
#pragma unroll
    for (int qs = 0; qs < 2; ++qs)
#pragma unroll
        for (int kd = 0; kd < 2; ++kd)
            aq[qs][kd] = *(const bf16x8*)(qb + (rowbase + bq + qs * 16 + l15) * D_MODEL
                                          + head * 64 + kd * 32 + lh * 8);

    float rsum[2] = {0.f, 0.f};

    stage_tile64(Kh, D_MODEL, Ks[0], w, lane);
    __syncthreads();

    for (int kt = 0; kt < NT; ++kt) {
        const int cur = kt & 1;
        if (kt + 1 < NT)
            stage_tile64(Kh + (size_t)(kt + 1) * 64 * D_MODEL, D_MODEL, Ks[cur ^ 1], w, lane);

        const char* kbuf = (const char*)Ks[cur];
        f32x4 s[2][4] = {};
#pragma unroll
        for (int fj = 0; fj < 4; ++fj) {
            int key = fj * 16 + l15;
            bf16x8 kf0 = *(const bf16x8*)(kbuf + key * 128 + ((lh ^ (key & 7)) << 4));
            bf16x8 kf1 = *(const bf16x8*)(kbuf + key * 128 + (((4 + lh) ^ (key & 7)) << 4));
#pragma unroll
            for (int qs = 0; qs < 2; ++qs) {
                s[qs][fj] = __builtin_amdgcn_mfma_f32_16x16x32_bf16(kf0, aq[qs][0], s[qs][fj], 0, 0, 0);
                s[qs][fj] = __builtin_amdgcn_mfma_f32_16x16x32_bf16(kf1, aq[qs][1], s[qs][fj], 0, 0, 0);
            }
        }
#pragma unroll
        for (int qs = 0; qs < 2; ++qs)
#pragma unroll
            for (int fj = 0; fj < 4; ++fj)
                rsum[qs] += (__expf(s[qs][fj][0]) + __expf(s[qs][fj][1]))
                          + (__expf(s[qs][fj][2]) + __expf(s[qs][fj][3]));
        __syncthreads();
    }

#pragma unroll
    for (int qs = 0; qs < 2; ++qs) {
        float v = rsum[qs];
        v += __shfl_xor(v, 16, 64);
        v += __shfl_xor(v, 32, 64);
        if (lh == 0)
            invl[(size_t)bh * SEQ + bq + qs * 16 + l15] = 1.0f / v;
    }
}

// ---------------------------------------------------------------------------
// Pass 1 (r8 structure + T4 counted vmcnt): QK^T recomputed, P = exp(s)*invl
// stored to global straight from registers; PV B-operand re-layout via
// wave-private LDS Ps[32][144B]; K/V^T double-buffered. Per-tile barrier is
// s_waitcnt vmcnt(8) + raw s_barrier: the 8 youngest vmem ops are this tile's
// P-stores (left in flight); the 4 older staging global_load_lds are
// guaranteed complete. No sched_barrier pinning. grid (64 bh, SEQ/128).
// ---------------------------------------------------------------------------
__global__ __launch_bounds__(256) void attn_pass1(
    const unsigned short* __restrict__ qb, const unsigned short* __restrict__ kb,
    const unsigned short* __restrict__ vt, const float* __restrict__ invl,
    float* __restrict__ attnP, unsigned short* __restrict__ ctx)
{
    __shared__ unsigned short Ks[2][64 * 64];   // 8 KB each
    __shared__ unsigned short Vs[2][64 * 64];   // 8 KB each (V^T rows = d)
    __shared__ unsigned short Ps[4][32 * 72];   // wave-private, 144B row stride
    const int bh = blockIdx.x, b = bh >> 4, head = bh & 15;
    const int tid = threadIdx.x;
    const int w = tid >> 6, lane = tid & 63, l15 = lane & 15, lh = lane >> 4;
    const int bq = blockIdx.y * 128 + w * 32;
    const size_t rowbase = (size_t)b * SEQ;
    const unsigned short* Kh = kb + rowbase * D_MODEL + head * 64;
    const unsigned short* Vh = vt + (size_t)bh * 64 * SEQ;    // [d][s]
    char* myPs = (char*)&Ps[w][0];

    bf16x8 aq[2][2];
    float invr[2];
    float* pdst[2];
#pragma unroll
    for (int qs = 0; qs < 2; ++qs) {
#pragma unroll
        for (int kd = 0; kd < 2; ++kd)
            aq[qs][kd] = *(const bf16x8*)(qb + (rowbase + bq + qs * 16 + l15) * D_MODEL
                                          + head * 64 + kd * 32 + lh * 8);
        invr[qs] = invl[(size_t)bh * SEQ + bq + qs * 16 + l15];
        pdst[qs] = attnP + ((size_t)bh * SEQ + bq + qs * 16 + l15) * SEQ + lh * 4;
    }

    f32x4 acc[2][4] = {};   // [qset][d-block]

    stage_tile64(Kh, D_MODEL, Ks[0], w, lane);
    stage_tile64(Vh, SEQ,     Vs[0], w, lane);
    __syncthreads();

    for (int kt = 0; kt < NT; ++kt) {
        const int cur = kt & 1;
        const int bk = kt * 64;
        if (kt + 1 < NT) {
            stage_tile64(Kh + (size_t)(bk + 64) * D_MODEL, D_MODEL, Ks[cur ^ 1], w, lane);
            stage_tile64(Vh + (size_t)(bk + 64),           SEQ,     Vs[cur ^ 1], w, lane);
        }

        // ---- QK^T : S^T[key][q] ----
        const char* kbuf = (const char*)Ks[cur];
        f32x4 s[2][4] = {};
#pragma unroll
        for (int fj = 0; fj < 4; ++fj) {
            int key = fj * 16 + l15;
            bf16x8 kf0 = *(const bf16x8*)(kbuf + key * 128 + ((lh ^ (key & 7)) << 4));
            bf16x8 kf1 = *(const bf16x8*)(kbuf + key * 128 + (((4 + lh) ^ (key & 7)) << 4));
#pragma unroll
            for (int qs = 0; qs < 2; ++qs) {
                s[qs][fj] = __builtin_amdgcn_mfma_f32_16x16x32_bf16(kf0, aq[qs][0], s[qs][fj], 0, 0, 0);
                s[qs][fj] = __builtin_amdgcn_mfma_f32_16x16x32_bf16(kf1, aq[qs][1], s[qs][fj], 0, 0, 0);
            }
        }

        // ---- exp*invl: P -> global fp32 direct from regs (8 stores);
        //      bf16 pack -> wave-private Ps for the PV B-operand ----
#pragma unroll
        for (int qs = 0; qs < 2; ++qs) {
#pragma unroll
            for (int fj = 0; fj < 4; ++fj) {
                float p0 = __expf(s[qs][fj][0]) * invr[qs];
                float p1 = __expf(s[qs][fj][1]) * invr[qs];
                float p2 = __expf(s[qs][fj][2]) * invr[qs];
                float p3 = __expf(s[qs][fj][3]) * invr[qs];
                float4 st = {p0, p1, p2, p3};
                *(float4*)(pdst[qs] + bk + fj * 16) = st;
                uint2 pk;
                pk.x = ((unsigned)f2bf(p1) << 16) | f2bf(p0);
                pk.y = ((unsigned)f2bf(p3) << 16) | f2bf(p2);
                *(uint2*)(myPs + (qs * 16 + l15) * 144 + fj * 32 + lh * 8) = pk;
            }
        }

        // ---- PV : O^T[d][q] += V^T[d][key] * P^T[key][q] ----
        const char* vbuf = (const char*)Vs[cur];
        bf16x8 pb[2][2];
#pragma unroll
        for (int qs = 0; qs < 2; ++qs)
#pragma unroll
            for (int ks = 0; ks < 2; ++ks)
                pb[qs][ks] = *(const bf16x8*)(myPs + (qs * 16 + l15) * 144 + ks * 64 + lh * 16);
#pragma unroll
        for (int db = 0; db < 4; ++db) {
            int d = db * 16 + l15;
            bf16x8 va0 = *(const bf16x8*)(vbuf + d * 128 + ((lh ^ (d & 7)) << 4));
            bf16x8 va1 = *(const bf16x8*)(vbuf + d * 128 + (((4 + lh) ^ (d & 7)) << 4));
#pragma unroll
            for (int qs = 0; qs < 2; ++qs) {
                acc[qs][db] = __builtin_amdgcn_mfma_f32_16x16x32_bf16(va0, pb[qs][0], acc[qs][db], 0, 0, 0);
                acc[qs][db] = __builtin_amdgcn_mfma_f32_16x16x32_bf16(va1, pb[qs][1], acc[qs][db], 0, 0, 0);
            }
        }

        if (kt + 1 < NT) {
            // Counted barrier (T4): leave this tile's 8 P-stores in flight;
            // guarantees the 4 older staging global_load_lds completed.
            asm volatile("s_waitcnt vmcnt(8)" ::: "memory");
            __builtin_amdgcn_s_barrier();
        }
    }

    // ---- ctx write: lane l15 = q, d = db*16 + lh*4 + r ----
#pragma unroll
    for (int qs = 0; qs < 2; ++qs)
#pragma unroll
        for (int db = 0; db < 4; ++db) {
            union { ushort4 u; uint2 v; } o;
            o.u.x = f2bf(acc[qs][db][0]); o.u.y = f2bf(acc[qs][db][1]);
            o.u.z = f2bf(acc[qs][db][2]); o.u.w = f2bf(acc[qs][db][3]);
            *(uint2*)&ctx[(rowbase + bq + qs * 16 + l15) * D_MODEL + head * 64 + db * 16 + lh * 4] = o.v;
        }
}

// ---------------------------------------------------------------------------
// LayerNorm over last dim (1024). 1 block/row.
// ---------------------------------------------------------------------------
__global__ __launch_bounds__(256) void layernorm_rows(
    const float* __restrict__ h, const float* __restrict__ gamma,
    const float* __restrict__ beta, float* __restrict__ out)
{
    const size_t row = blockIdx.x;
    const float* hr = h + row * D_MODEL;
    const int tid = threadIdx.x;

    float v[4];
    float s = 0.f;
#pragma unroll
    for (int i = 0; i < 4; ++i) { v[i] = hr[tid + i * 256]; s += v[i]; }
    __shared__ float red[256];
    red[tid] = s;
    __syncthreads();
    for (int st = 128; st > 0; st >>= 1) {
        if (tid < st) red[tid] += red[tid + st];
        __syncthreads();
    }
    float mean = red[0] * (1.0f / D_MODEL);
    __syncthreads();

    float vs = 0.f;
#pragma unroll
    for (int i = 0; i < 4; ++i) { float d = v[i] - mean; vs += d * d; }
    red[tid] = vs;
    __syncthreads();
    for (int st = 128; st > 0; st >>= 1) {
        if (tid < st) red[tid] += red[tid + st];
        __syncthreads();
    }
    float inv = rsqrtf(red[0] * (1.0f / D_MODEL) + EPS);

#pragma unroll
    for (int i = 0; i < 4; ++i) {
        int c = tid + i * 256;
        out[row * D_MODEL + c] = (v[i] - mean) * inv * gamma[c] + beta[c];
    }
}

// ---------------------------------------------------------------------------
extern "C" void kernel_launch(void* const* d_in, const int* in_sizes, int n_in,
                              void* d_out, int out_size, void* d_ws, size_t ws_size,
                              hipStream_t stream)
{
    const float* x     = (const float*)d_in[0];
    const float* Wq    = (const float*)d_in[1];
    const float* bq_   = (const float*)d_in[2];
    const float* Wk    = (const float*)d_in[3];
    const float* bk_   = (const float*)d_in[4];
    const float* Wv    = (const float*)d_in[5];
    const float* bv_   = (const float*)d_in[6];
    const float* Wo    = (const float*)d_in[7];
    const float* bo_   = (const float*)d_in[8];
    const float* gamma = (const float*)d_in[9];
    const float* beta  = (const float*)d_in[10];

    const size_t NX = (size_t)BATCH * SEQ * D_MODEL;   // 8388608
    const size_t NW = (size_t)D_MODEL * D_MODEL;       // 1048576

    float* out_ln = (float*)d_out;
    float* attnP  = out_ln + NX;

    unsigned short* x_bf   = (unsigned short*)d_ws;
    unsigned short* wq_bf  = x_bf + NX;
    unsigned short* wk_bf  = wq_bf + NW;
    unsigned short* wv_bf  = wk_bf + NW;
    unsigned short* wo_bf  = wv_bf + NW;
    unsigned short* q_bf   = wo_bf + NW;
    unsigned short* k_bf   = q_bf + NX;
    unsigned short* vt_bf  = k_bf + NX;                // V, stored transposed [bh][d][s]
    unsigned short* ctx_bf = vt_bf + NX;
    float* invl = (float*)(ctx_bf + NX);               // 64*2048 f32
    float* hbuf = (float*)q_bf;                        // reuse q+k region (f32 NX)

    const int M = BATCH * SEQ;   // 8192

    cvt_all<<<12288, 256, 0, stream>>>(x, Wq, Wk, Wv, Wo,
                                       x_bf, wq_bf, wk_bf, wv_bf, wo_bf);

    gemm_qkv<<<dim3(24, M / 128), 256, 0, stream>>>(
        x_bf, wq_bf, wk_bf, wv_bf, bq_, bk_, bv_, q_bf, k_bf, vt_bf);

    attn_pass0<<<dim3(BATCH * N_HEADS, SEQ / 128), 256, 0, stream>>>(q_bf, k_bf, invl);

    attn_pass1<<<dim3(BATCH * N_HEADS, SEQ / 128), 256, 0, stream>>>(
        q_bf, k_bf, vt_bf, invl, attnP, ctx_bf);

    gemm_out<<<dim3(D_MODEL / 128, M / 128), 256, 0, stream>>>(
        ctx_bf, wo_bf, bo_, x, hbuf);

    layernorm_rows<<<M, 256, 0, stream>>>(hbuf, gamma, beta, out_ln);
}